// Round 1
// baseline (187.705 us; speedup 1.0000x reference)
//
#include <hip/hip_runtime.h>
#include <stdint.h>

#define BATCH 16
#define NPTS  20000
#define TOPK  1000

__device__ __forceinline__ uint32_t key_desc(float f) {
    // ascending transform, then invert -> sorting ascending by k gives cls descending
    uint32_t u = __float_as_uint(f);
    uint32_t m = (u & 0x80000000u) ? ~u : (u | 0x80000000u);
    return ~m;
}

// ---------------- Kernel A: exact stable top-1000 per batch ----------------
__global__ __launch_bounds__(1024) void topk_kernel(
    const float* __restrict__ reg, const float* __restrict__ cls,
    float4* __restrict__ ws_boxes, float* __restrict__ ws_cls)
{
    __shared__ uint32_t hist[256];
    __shared__ uint32_t sh_kpfx;   // k32 prefix
    __shared__ uint32_t sh_ipfx;   // idx prefix
    __shared__ int      sh_r;
    __shared__ int      sh_cnt;
    __shared__ uint64_t sel[1024];

    const int b   = blockIdx.x;
    const int tid = threadIdx.x;
    const float* c = cls + (size_t)b * NPTS;

    if (tid == 0) { sh_r = TOPK - 1; sh_kpfx = 0; sh_ipfx = 0; sh_cnt = 0; }
    __syncthreads();

    // --- 4 radix passes over k32 (find k-value of rank 999 ascending) ---
    uint32_t kpfx = 0, kmask = 0;
    for (int pass = 0; pass < 4; ++pass) {
        for (int i = tid; i < 256; i += 1024) hist[i] = 0;
        __syncthreads();
        const int shift = 24 - 8 * pass;
        for (int p = tid; p < NPTS; p += 1024) {
            uint32_t k = key_desc(c[p]);
            if ((k & kmask) == kpfx) atomicAdd(&hist[(k >> shift) & 255], 1u);
        }
        __syncthreads();
        if (tid == 0) {
            int r = sh_r; uint32_t cum = 0; int digit = 255;
            for (int bin = 0; bin < 256; ++bin) {
                uint32_t h = hist[bin];
                if (cum + h > (uint32_t)r) { digit = bin; break; }
                cum += h;
            }
            sh_r = r - (int)cum;
            sh_kpfx = kpfx | ((uint32_t)digit << shift);
        }
        __syncthreads();
        kpfx = sh_kpfx;
        kmask |= (0xFFu << shift);
    }
    const uint32_t kth = kpfx;

    // --- 2 radix passes over index (tie-break among equal k32, ascending) ---
    uint32_t ipfx = 0, imask = 0;
    for (int pass = 0; pass < 2; ++pass) {
        for (int i = tid; i < 256; i += 1024) hist[i] = 0;
        __syncthreads();
        const int shift = 8 - 8 * pass;
        for (int p = tid; p < NPTS; p += 1024) {
            uint32_t k = key_desc(c[p]);
            if (k == kth && (((uint32_t)p) & imask) == ipfx)
                atomicAdd(&hist[((uint32_t)p >> shift) & 255], 1u);
        }
        __syncthreads();
        if (tid == 0) {
            int r = sh_r; uint32_t cum = 0; int digit = 255;
            for (int bin = 0; bin < 256; ++bin) {
                uint32_t h = hist[bin];
                if (cum + h > (uint32_t)r) { digit = bin; break; }
                cum += h;
            }
            sh_r = r - (int)cum;
            sh_ipfx = ipfx | ((uint32_t)digit << shift);
        }
        __syncthreads();
        ipfx = sh_ipfx;
        imask |= (0xFFu << shift);
    }
    const uint64_t kthkey = ((uint64_t)kth << 32) | (uint64_t)ipfx;

    // --- gather exactly 1000 keys <= kthkey ---
    sel[tid] = ~0ull;
    __syncthreads();
    for (int p = tid; p < NPTS; p += 1024) {
        uint64_t key = ((uint64_t)key_desc(c[p]) << 32) | (uint32_t)p;
        if (key <= kthkey) {
            int pos = atomicAdd(&sh_cnt, 1);
            sel[pos] = key;
        }
    }
    __syncthreads();

    // --- bitonic sort 1024 (ascending; pad = UINT64_MAX goes last) ---
    for (int k = 2; k <= 1024; k <<= 1) {
        for (int j = k >> 1; j > 0; j >>= 1) {
            int ixj = tid ^ j;
            if (ixj > tid) {
                uint64_t a = sel[tid], bb = sel[ixj];
                bool up = (tid & k) == 0;
                if ((a > bb) == up) { sel[tid] = bb; sel[ixj] = a; }
            }
            __syncthreads();
        }
    }

    // --- write sorted boxes + scores ---
    if (tid < TOPK) {
        uint64_t key = sel[tid];
        int p = (int)(key & 0xFFFFFFFFu);
        ws_boxes[b * TOPK + tid] = ((const float4*)reg)[(size_t)b * NPTS + p];
        ws_cls[b * TOPK + tid] = c[p];
    }
}

// ---------------- Kernel B: suppression bitmask (iou >= 0.5) ----------------
__global__ __launch_bounds__(256) void iou_kernel(
    const float4* __restrict__ ws_boxes, uint64_t* __restrict__ ws_supp)
{
    __shared__ float4 boxes[TOPK];
    const int b     = blockIdx.y;
    const int chunk = blockIdx.x;     // 0..15, 63 rows each (1008 >= 1000)
    const int tid   = threadIdx.x;
    for (int j = tid; j < TOPK; j += 256) boxes[j] = ws_boxes[b * TOPK + j];
    __syncthreads();

    const int lane = tid & 63;
    const int wave = tid >> 6;        // 0..3
    const int rbeg = chunk * 63;
    const int rend = (rbeg + 63 < TOPK) ? (rbeg + 63) : TOPK;

    for (int i = rbeg + wave; i < rend; i += 4) {
        float4 a = boxes[i];
        float areaA = (a.z - a.x) * (a.w - a.y);
        uint64_t mine = 0;
        #pragma unroll
        for (int w = 0; w < 16; ++w) {
            int col = (w << 6) | lane;
            bool sup = false;
            if (col < TOPK) {
                float4 bb = boxes[col];
                float xx1 = fmaxf(a.x, bb.x);
                float yy1 = fmaxf(a.y, bb.y);
                float xx2 = fminf(a.z, bb.z);
                float yy2 = fminf(a.w, bb.w);
                float iw = fmaxf(xx2 - xx1, 0.0f);
                float ih = fmaxf(yy2 - yy1, 0.0f);
                float inter = iw * ih;
                float areaB = (bb.z - bb.x) * (bb.w - bb.y);
                float iou = inter / (areaA + areaB - inter);
                sup = (iou >= 0.5f);
            }
            uint64_t m = __ballot(sup);
            if (lane == w) mine = m;
        }
        if (lane < 16)
            ws_supp[((size_t)b * TOPK + i) * 16 + lane] = mine;
    }
}

// ---------------- Kernel C: sequential greedy sweep + output ----------------
__global__ __launch_bounds__(256) void sweep_kernel(
    const uint64_t* __restrict__ ws_supp, const float4* __restrict__ ws_boxes,
    const float* __restrict__ ws_cls, float* __restrict__ out)
{
    // 4 chunks of 250 rows; double-buffered (2 * 250 * 32 * 4B = 64000 B)
    __shared__ uint32_t buf[2][250 * 32];
    __shared__ uint32_t keptw[32];

    const int b    = blockIdx.x;
    const int tid  = threadIdx.x;
    const int wave = tid >> 6;
    const uint32_t* g = (const uint32_t*)(ws_supp + (size_t)b * TOPK * 16);

    // preload chunk 0
    for (int idx = tid; idx < 8000; idx += 256) buf[0][idx] = g[idx];
    __syncthreads();

    uint32_t remv = 0, kept = 0;
    int curw = -1; uint32_t rw = 0;
    const int myw = tid & 31;

    for (int cch = 0; cch < 4; ++cch) {
        if (wave != 0 && cch + 1 < 4) {
            for (int idx = tid - 64; idx < 8000; idx += 192)
                buf[(cch + 1) & 1][idx] = g[(cch + 1) * 8000 + idx];
        }
        if (wave == 0) {
            const uint32_t* rows = buf[cch & 1];
            for (int ii = 0; ii < 250; ++ii) {
                const int i = cch * 250 + ii;
                const int w = i >> 5, bit = i & 31;
                if (w != curw) { rw = __shfl(remv, w); curw = w; }
                uint32_t row = rows[ii * 32 + myw];
                if (!((rw >> bit) & 1u)) {          // uniform across wave
                    if (tid == w) kept |= (1u << bit);
                    remv |= row;
                    rw = __shfl(remv, w);
                }
            }
        }
        __syncthreads();
    }

    if (tid < 32) keptw[tid] = kept;
    __syncthreads();

    const float4* bx = ws_boxes + (size_t)b * TOPK;
    const float*  bc = ws_cls + (size_t)b * TOPK;
    float4* outr = (float4*)out + (size_t)b * TOPK;
    float*  outc = out + (size_t)BATCH * TOPK * 4 + (size_t)b * TOPK;
    for (int j = tid; j < TOPK; j += 256) {
        bool keep = (keptw[j >> 5] >> (j & 31)) & 1u;
        float4 v = bx[j];
        float cv = bc[j];
        outr[j] = keep ? v : make_float4(0.f, 0.f, 0.f, 0.f);
        outc[j] = keep ? cv : 0.0f;
    }
}

extern "C" void kernel_launch(void* const* d_in, const int* in_sizes, int n_in,
                              void* d_out, int out_size, void* d_ws, size_t ws_size,
                              hipStream_t stream) {
    (void)in_sizes; (void)n_in; (void)out_size; (void)ws_size;
    const float* reg = (const float*)d_in[0];
    const float* cls = (const float*)d_in[1];
    float* out = (float*)d_out;
    char* ws = (char*)d_ws;

    float4*   ws_boxes = (float4*)ws;                       // 16*1000*16 = 256000 B
    float*    ws_cls   = (float*)(ws + 256000);             // 64000 B
    uint64_t* ws_supp  = (uint64_t*)(ws + 256000 + 64000);  // 16*1000*16*8 = 2048000 B

    topk_kernel<<<dim3(BATCH), dim3(1024), 0, stream>>>(reg, cls, ws_boxes, ws_cls);
    iou_kernel<<<dim3(16, BATCH), dim3(256), 0, stream>>>(ws_boxes, ws_supp);
    sweep_kernel<<<dim3(BATCH), dim3(256), 0, stream>>>(ws_supp, ws_boxes, ws_cls, out);
}

// Round 2
// 92.584 us; speedup vs baseline: 2.0274x; 2.0274x over previous
//
#include <hip/hip_runtime.h>
#include <stdint.h>

#define BATCH 16
#define NPTS  20000
#define TOPK  1000

__device__ __forceinline__ uint32_t key_desc(float f) {
    // ascending transform, then invert -> sorting ascending by k gives cls descending
    uint32_t u = __float_as_uint(f);
    uint32_t m = (u & 0x80000000u) ? ~u : (u | 0x80000000u);
    return ~m;
}

// Parallel radix digit-find: wave 0 scans the 256-bin histogram, locates the
// bin containing rank r, updates *sh_r and ORs digit<<shift into *sh_pfx.
__device__ __forceinline__ void digit_find(uint32_t* hist, int* sh_r,
                                           uint32_t* sh_pfx, int shift, int tid) {
    if (tid < 64) {
        int r = *sh_r;
        uint32_t v0 = hist[4 * tid + 0], v1 = hist[4 * tid + 1];
        uint32_t v2 = hist[4 * tid + 2], v3 = hist[4 * tid + 3];
        uint32_t s = v0 + v1 + v2 + v3;
        uint32_t x = s;
        #pragma unroll
        for (int d = 1; d < 64; d <<= 1) {
            uint32_t t = __shfl_up(x, d);
            if (tid >= d) x += t;
        }
        uint32_t e0 = x - s;                       // exclusive prefix of this lane's 4 bins
        uint32_t e1 = e0 + v0, e2 = e1 + v1, e3 = e2 + v2, e4 = e3 + v3;
        uint32_t ur = (uint32_t)r;
        if (ur >= e0 && ur < e4) {                 // exactly one lane
            int digit; uint32_t eSel;
            if      (ur < e1) { digit = 4 * tid + 0; eSel = e0; }
            else if (ur < e2) { digit = 4 * tid + 1; eSel = e1; }
            else if (ur < e3) { digit = 4 * tid + 2; eSel = e2; }
            else              { digit = 4 * tid + 3; eSel = e3; }
            *sh_r = r - (int)eSel;
            *sh_pfx |= ((uint32_t)digit << shift);
        }
    }
}

// ---------------- Kernel A: exact stable top-1000 per batch ----------------
__global__ __launch_bounds__(1024) void topk_kernel(
    const float* __restrict__ reg, const float* __restrict__ cls,
    float4* __restrict__ ws_boxes, float* __restrict__ ws_cls)
{
    __shared__ uint32_t hist[256];
    __shared__ uint32_t sh_kpfx;   // k32 prefix
    __shared__ uint32_t sh_ipfx;   // idx prefix
    __shared__ int      sh_r;
    __shared__ int      sh_cnt;
    __shared__ uint64_t sel[1024];

    const int b   = blockIdx.x;
    const int tid = threadIdx.x;
    const float* c = cls + (size_t)b * NPTS;

    if (tid == 0) { sh_r = TOPK - 1; sh_kpfx = 0; sh_ipfx = 0; sh_cnt = 0; }
    __syncthreads();

    // --- 4 radix passes over k32 (find k-value of rank 999 ascending) ---
    uint32_t kpfx = 0, kmask = 0;
    for (int pass = 0; pass < 4; ++pass) {
        for (int i = tid; i < 256; i += 1024) hist[i] = 0;
        __syncthreads();
        const int shift = 24 - 8 * pass;
        for (int p = tid; p < NPTS; p += 1024) {
            uint32_t k = key_desc(c[p]);
            if ((k & kmask) == kpfx) atomicAdd(&hist[(k >> shift) & 255], 1u);
        }
        __syncthreads();
        digit_find(hist, &sh_r, &sh_kpfx, shift, tid);
        __syncthreads();
        kpfx = sh_kpfx;
        kmask |= (0xFFu << shift);
    }
    const uint32_t kth = kpfx;

    // --- 2 radix passes over index (tie-break among equal k32, ascending) ---
    uint32_t ipfx = 0, imask = 0;
    for (int pass = 0; pass < 2; ++pass) {
        for (int i = tid; i < 256; i += 1024) hist[i] = 0;
        __syncthreads();
        const int shift = 8 - 8 * pass;
        for (int p = tid; p < NPTS; p += 1024) {
            uint32_t k = key_desc(c[p]);
            if (k == kth && (((uint32_t)p) & imask) == ipfx)
                atomicAdd(&hist[((uint32_t)p >> shift) & 255], 1u);
        }
        __syncthreads();
        digit_find(hist, &sh_r, &sh_ipfx, shift, tid);
        __syncthreads();
        ipfx = sh_ipfx;
        imask |= (0xFFu << shift);
    }
    const uint64_t kthkey = ((uint64_t)kth << 32) | (uint64_t)ipfx;

    // --- gather exactly 1000 keys <= kthkey ---
    sel[tid] = ~0ull;
    __syncthreads();
    for (int p = tid; p < NPTS; p += 1024) {
        uint64_t key = ((uint64_t)key_desc(c[p]) << 32) | (uint32_t)p;
        if (key <= kthkey) {
            int pos = atomicAdd(&sh_cnt, 1);
            sel[pos] = key;
        }
    }
    __syncthreads();

    // --- bitonic sort 1024 (ascending; pad = UINT64_MAX goes last) ---
    for (int k = 2; k <= 1024; k <<= 1) {
        for (int j = k >> 1; j > 0; j >>= 1) {
            int ixj = tid ^ j;
            if (ixj > tid) {
                uint64_t a = sel[tid], bb = sel[ixj];
                bool up = (tid & k) == 0;
                if ((a > bb) == up) { sel[tid] = bb; sel[ixj] = a; }
            }
            __syncthreads();
        }
    }

    // --- write sorted boxes + scores ---
    if (tid < TOPK) {
        uint64_t key = sel[tid];
        int p = (int)(key & 0xFFFFFFFFu);
        ws_boxes[b * TOPK + tid] = ((const float4*)reg)[(size_t)b * NPTS + p];
        ws_cls[b * TOPK + tid] = c[p];
    }
}

// ---------------- Kernel B: suppression bitmask, TRANSPOSED layout ----------
// suppT[b][word w][row i] = bits: columns 32w..32w+31 of supp row i.
__global__ __launch_bounds__(256) void iou_kernel(
    const float4* __restrict__ ws_boxes, uint32_t* __restrict__ suppT)
{
    __shared__ float4 boxes[TOPK];
    const int b     = blockIdx.y;
    const int chunk = blockIdx.x;     // 0..15, 63 rows each (1008 >= 1000)
    const int tid   = threadIdx.x;
    for (int j = tid; j < TOPK; j += 256) boxes[j] = ws_boxes[b * TOPK + j];
    __syncthreads();

    const int lane = tid & 63;
    const int wave = tid >> 6;        // 0..3
    const int rbeg = chunk * 63;
    const int rend = (rbeg + 63 < TOPK) ? (rbeg + 63) : TOPK;
    uint32_t* t = suppT + (size_t)b * 32 * 1024;

    for (int i = rbeg + wave; i < rend; i += 4) {
        float4 a = boxes[i];
        float areaA = (a.z - a.x) * (a.w - a.y);
        uint64_t mine = 0;
        #pragma unroll
        for (int w = 0; w < 16; ++w) {
            int col = (w << 6) | lane;
            bool sup = false;
            if (col < TOPK) {
                float4 bb = boxes[col];
                float xx1 = fmaxf(a.x, bb.x);
                float yy1 = fmaxf(a.y, bb.y);
                float xx2 = fminf(a.z, bb.z);
                float yy2 = fminf(a.w, bb.w);
                float iw = fmaxf(xx2 - xx1, 0.0f);
                float ih = fmaxf(yy2 - yy1, 0.0f);
                float inter = iw * ih;
                float areaB = (bb.z - bb.x) * (bb.w - bb.y);
                float iou = inter / (areaA + areaB - inter);
                sup = (iou >= 0.5f);
            }
            uint64_t m = __ballot(sup);
            if (lane == w) mine = m;
        }
        if (lane < 16) {
            t[(2 * lane + 0) * 1024 + i] = (uint32_t)(mine & 0xFFFFFFFFull);
            t[(2 * lane + 1) * 1024 + i] = (uint32_t)(mine >> 32);
        }
    }
}

// ---------------- Kernel C: group-32 greedy sweep + output ----------------
// One wave per batch. remv distributed: lane m holds removed-word m.
// Per group w (rows 32w..32w+31): decisions via broadcast diagonal block
// (uniform in-register chain), updates via per-lane column slice.
__global__ __launch_bounds__(64) void sweep_kernel(
    const uint32_t* __restrict__ suppT, const float4* __restrict__ ws_boxes,
    const float* __restrict__ ws_cls, float* __restrict__ out)
{
    const int b    = blockIdx.x;
    const int lane = threadIdx.x;
    const int myw  = lane & 31;
    const uint32_t* base = suppT + (size_t)b * 32 * 1024;

    uint32_t remv = 0, keptw = 0;
    uint4 dgA[8], clA[8], dgB[8], clB[8];

#define LOADG(W, DG, CL) { \
    const uint4* dp_ = (const uint4*)(base + (W) * 1024 + (W) * 32); \
    const uint4* cp_ = (const uint4*)(base + myw * 1024 + (W) * 32); \
    _Pragma("unroll") \
    for (int k_ = 0; k_ < 8; ++k_) { DG[k_] = dp_[k_]; CL[k_] = cp_[k_]; } }

#define STEP(D, C, BBIT) { \
    uint32_t live_ = (((~cur) >> (BBIT)) & 1u) & (uint32_t)((BBIT) < nb); \
    uint32_t msk_ = (uint32_t)0 - live_; \
    kmask |= (live_ << (BBIT)); \
    cur  |= (D) & msk_; \
    acc  |= (C) & msk_; }

#define PROC(W, DG, CL) { \
    const int nb = ((W) == 31) ? (TOPK - 31 * 32) : 32; \
    uint32_t cur = __shfl(remv, (W)); \
    uint32_t kmask = 0, acc = 0; \
    _Pragma("unroll") \
    for (int k_ = 0; k_ < 8; ++k_) { \
        STEP(DG[k_].x, CL[k_].x, 4 * k_ + 0); \
        STEP(DG[k_].y, CL[k_].y, 4 * k_ + 1); \
        STEP(DG[k_].z, CL[k_].z, 4 * k_ + 2); \
        STEP(DG[k_].w, CL[k_].w, 4 * k_ + 3); \
    } \
    remv |= acc; \
    if (myw == (W)) keptw = kmask; }

    LOADG(0, dgA, clA);
    #pragma unroll 1
    for (int w2 = 0; w2 < 16; ++w2) {
        const int wE = 2 * w2, wO = 2 * w2 + 1;
        LOADG(wO, dgB, clB);          // prefetch odd group
        PROC(wE, dgA, clA);
        if (wO + 1 < 32) LOADG(wO + 1, dgA, clA);   // prefetch next even group
        PROC(wO, dgB, clB);
    }

    __shared__ uint32_t skept[32];
    if (lane < 32) skept[lane] = keptw;
    __syncthreads();

    const float4* bx = ws_boxes + (size_t)b * TOPK;
    const float*  bc = ws_cls + (size_t)b * TOPK;
    float4* outr = (float4*)out + (size_t)b * TOPK;
    float*  outc = out + (size_t)BATCH * TOPK * 4 + (size_t)b * TOPK;
    for (int j = lane; j < TOPK; j += 64) {
        uint32_t keep = (skept[j >> 5] >> (j & 31)) & 1u;
        float4 v = bx[j];
        float cv = bc[j];
        outr[j] = keep ? v : make_float4(0.f, 0.f, 0.f, 0.f);
        outc[j] = keep ? cv : 0.0f;
    }
#undef LOADG
#undef STEP
#undef PROC
}

extern "C" void kernel_launch(void* const* d_in, const int* in_sizes, int n_in,
                              void* d_out, int out_size, void* d_ws, size_t ws_size,
                              hipStream_t stream) {
    (void)in_sizes; (void)n_in; (void)out_size; (void)ws_size;
    const float* reg = (const float*)d_in[0];
    const float* cls = (const float*)d_in[1];
    float* out = (float*)d_out;
    char* ws = (char*)d_ws;

    float4*   ws_boxes = (float4*)ws;                      // 16*1000*16 = 256000 B
    float*    ws_cls   = (float*)(ws + 256000);            // 64000 B
    uint32_t* suppT    = (uint32_t*)(ws + 320000);         // 16*32*1024*4 = 2097152 B

    topk_kernel<<<dim3(BATCH), dim3(1024), 0, stream>>>(reg, cls, ws_boxes, ws_cls);
    iou_kernel<<<dim3(16, BATCH), dim3(256), 0, stream>>>(ws_boxes, suppT);
    sweep_kernel<<<dim3(BATCH), dim3(64), 0, stream>>>(suppT, ws_boxes, ws_cls, out);
}

// Round 3
// 74.704 us; speedup vs baseline: 2.5126x; 1.2393x over previous
//
#include <hip/hip_runtime.h>
#include <stdint.h>

#define BATCH 16
#define NPTS  20000
#define TOPK  1000

__device__ __forceinline__ uint32_t key_desc(float f) {
    // ascending transform, then invert -> sorting ascending by k gives cls descending
    uint32_t u = __float_as_uint(f);
    uint32_t m = (u & 0x80000000u) ? ~u : (u | 0x80000000u);
    return ~m;
}

__device__ __forceinline__ float key_undo(uint32_t k) {
    uint32_t m = ~k;
    uint32_t u = (m & 0x80000000u) ? (m & 0x7FFFFFFFu) : ~m;
    return __uint_as_float(u);
}

// Parallel radix digit-find: wave 0 scans the 256-bin histogram, locates the
// bin containing rank r, updates *sh_r and ORs digit<<shift into *sh_pfx.
__device__ __forceinline__ void digit_find(const uint32_t* hist, int* sh_r,
                                           uint32_t* sh_pfx, int shift, int tid) {
    if (tid < 64) {
        int r = *sh_r;
        uint32_t v0 = hist[4 * tid + 0], v1 = hist[4 * tid + 1];
        uint32_t v2 = hist[4 * tid + 2], v3 = hist[4 * tid + 3];
        uint32_t s = v0 + v1 + v2 + v3;
        uint32_t x = s;
        #pragma unroll
        for (int d = 1; d < 64; d <<= 1) {
            uint32_t t = __shfl_up(x, d);
            if (tid >= d) x += t;
        }
        uint32_t e0 = x - s;                       // exclusive prefix of this lane's 4 bins
        uint32_t e1 = e0 + v0, e2 = e1 + v1, e3 = e2 + v2, e4 = e3 + v3;
        uint32_t ur = (uint32_t)r;
        if (ur >= e0 && ur < e4) {                 // exactly one lane
            int digit; uint32_t eSel;
            if      (ur < e1) { digit = 4 * tid + 0; eSel = e0; }
            else if (ur < e2) { digit = 4 * tid + 1; eSel = e1; }
            else if (ur < e3) { digit = 4 * tid + 2; eSel = e2; }
            else              { digit = 4 * tid + 3; eSel = e3; }
            *sh_r = r - (int)eSel;
            *sh_pfx |= ((uint32_t)digit << shift);
        }
    }
}

// ---------------- Kernel A: exact stable top-1000 per batch ----------------
__global__ __launch_bounds__(1024) void topk_kernel(
    const float* __restrict__ reg, const float* __restrict__ cls,
    float4* __restrict__ ws_boxes, float* __restrict__ ws_cls)
{
    __shared__ uint32_t whist[16][256];   // per-wave histograms
    __shared__ uint32_t merged[256];
    __shared__ uint32_t sh_kpfx;
    __shared__ uint32_t sh_ipfx;
    __shared__ int      sh_r;
    __shared__ int      sh_cnt;
    __shared__ uint64_t sel[1024];

    const int b    = blockIdx.x;
    const int tid  = threadIdx.x;
    const int wave = tid >> 6;
    const float* c = cls + (size_t)b * NPTS;

    if (tid == 0) { sh_r = TOPK - 1; sh_kpfx = 0; sh_ipfx = 0; sh_cnt = 0; }

    // --- cache all keys in registers (20 per thread, fixed unroll) ---
    uint32_t kreg[20];
    #pragma unroll
    for (int j = 0; j < 20; ++j) {
        int p = tid + j * 1024;
        kreg[j] = (p < NPTS) ? key_desc(c[p]) : 0xFFFFFFFFu;
    }
    __syncthreads();

    // --- 4 radix passes over k32 (find k-value of rank 999 ascending) ---
    uint32_t kpfx = 0, kmask = 0;
    for (int pass = 0; pass < 4; ++pass) {
        for (int i = tid; i < 16 * 256; i += 1024) ((uint32_t*)whist)[i] = 0;
        __syncthreads();
        const int shift = 24 - 8 * pass;
        #pragma unroll
        for (int j = 0; j < 20; ++j) {
            int p = tid + j * 1024;
            uint32_t k = kreg[j];
            if (p < NPTS && (k & kmask) == kpfx)
                atomicAdd(&whist[wave][(k >> shift) & 255], 1u);
        }
        __syncthreads();
        if (tid < 256) {
            uint32_t s = 0;
            #pragma unroll
            for (int w2 = 0; w2 < 16; ++w2) s += whist[w2][tid];
            merged[tid] = s;
        }
        __syncthreads();
        digit_find(merged, &sh_r, &sh_kpfx, shift, tid);
        __syncthreads();
        kpfx = sh_kpfx;
        kmask |= (0xFFu << shift);
    }
    const uint32_t kth = kpfx;
    const uint32_t kthcnt = merged[kth & 255];   // #elements with full key == kth

    // --- index tie-break (rare): 2 radix passes over 16-bit index ---
    uint32_t ipfx = 0;
    if (kthcnt > 1) {
        uint32_t imask = 0;
        for (int pass = 0; pass < 2; ++pass) {
            for (int i = tid; i < 16 * 256; i += 1024) ((uint32_t*)whist)[i] = 0;
            __syncthreads();
            const int shift = 8 - 8 * pass;
            #pragma unroll
            for (int j = 0; j < 20; ++j) {
                int p = tid + j * 1024;
                if (p < NPTS && kreg[j] == kth && (((uint32_t)p) & imask) == ipfx)
                    atomicAdd(&whist[wave][((uint32_t)p >> shift) & 255], 1u);
            }
            __syncthreads();
            if (tid < 256) {
                uint32_t s = 0;
                #pragma unroll
                for (int w2 = 0; w2 < 16; ++w2) s += whist[w2][tid];
                merged[tid] = s;
            }
            __syncthreads();
            digit_find(merged, &sh_r, &sh_ipfx, shift, tid);
            __syncthreads();
            ipfx = sh_ipfx;
            imask |= (0xFFu << shift);
        }
    } else {
        ipfx = 0xFFFFFFFFu;   // unique kth key: any index bound selects it
    }
    const uint64_t kthkey = ((uint64_t)kth << 32) | (uint64_t)ipfx;

    // --- gather exactly 1000 keys <= kthkey ---
    sel[tid] = ~0ull;
    __syncthreads();
    #pragma unroll
    for (int j = 0; j < 20; ++j) {
        int p = tid + j * 1024;
        if (p < NPTS) {
            uint64_t key = ((uint64_t)kreg[j] << 32) | (uint32_t)p;
            if (key <= kthkey) {
                int pos = atomicAdd(&sh_cnt, 1);
                sel[pos] = key;
            }
        }
    }
    __syncthreads();

    // --- hybrid bitonic sort 1024 (LDS only for j>=64; shuffles for j<=32) ---
    uint64_t v = sel[tid];
    for (int k = 2; k <= 1024; k <<= 1) {
        for (int j = k >> 1; j >= 64; j >>= 1) {
            __syncthreads();
            sel[tid] = v;
            __syncthreads();
            uint64_t o = sel[tid ^ j];
            bool upper = (tid & j) != 0;
            bool asc   = (tid & k) == 0;
            v = (upper == asc) ? (v > o ? v : o) : (v < o ? v : o);
        }
        int j0 = (k >> 1) < 64 ? (k >> 1) : 32;
        for (int j = j0; j >= 1; j >>= 1) {
            uint64_t o = __shfl_xor(v, j);
            bool upper = (tid & j) != 0;
            bool asc   = (tid & k) == 0;
            v = (upper == asc) ? (v > o ? v : o) : (v < o ? v : o);
        }
    }

    // --- write sorted boxes + scores ---
    if (tid < TOPK) {
        int p = (int)(v & 0xFFFFFFFFull);
        ws_boxes[b * TOPK + tid] = ((const float4*)reg)[(size_t)b * NPTS + p];
        ws_cls[b * TOPK + tid] = key_undo((uint32_t)(v >> 32));
    }
}

// ---------------- Kernel B: suppression bitmask, TRANSPOSED layout ----------
// suppT[b][word w][row i] = bits: columns 32w..32w+31 of supp row i.
__global__ __launch_bounds__(256) void iou_kernel(
    const float4* __restrict__ ws_boxes, uint32_t* __restrict__ suppT)
{
    __shared__ float4 boxes[TOPK];
    const int b     = blockIdx.y;
    const int chunk = blockIdx.x;     // 0..15, 63 rows each (1008 >= 1000)
    const int tid   = threadIdx.x;
    for (int j = tid; j < TOPK; j += 256) boxes[j] = ws_boxes[b * TOPK + j];
    __syncthreads();

    const int lane = tid & 63;
    const int wave = tid >> 6;        // 0..3
    const int rbeg = chunk * 63;
    const int rend = (rbeg + 63 < TOPK) ? (rbeg + 63) : TOPK;
    uint32_t* t = suppT + (size_t)b * 32 * 1024;

    for (int i = rbeg + wave; i < rend; i += 4) {
        float4 a = boxes[i];
        float areaA = (a.z - a.x) * (a.w - a.y);
        uint64_t mine = 0;
        #pragma unroll
        for (int w = 0; w < 16; ++w) {
            int col = (w << 6) | lane;
            bool sup = false;
            if (col < TOPK) {
                float4 bb = boxes[col];
                float xx1 = fmaxf(a.x, bb.x);
                float yy1 = fmaxf(a.y, bb.y);
                float xx2 = fminf(a.z, bb.z);
                float yy2 = fminf(a.w, bb.w);
                float iw = fmaxf(xx2 - xx1, 0.0f);
                float ih = fmaxf(yy2 - yy1, 0.0f);
                float inter = iw * ih;
                float areaB = (bb.z - bb.x) * (bb.w - bb.y);
                float iou = inter / (areaA + areaB - inter);
                sup = (iou >= 0.5f);
            }
            uint64_t m = __ballot(sup);
            if (lane == w) mine = m;
        }
        if (lane < 16) {
            t[(2 * lane + 0) * 1024 + i] = (uint32_t)(mine & 0xFFFFFFFFull);
            t[(2 * lane + 1) * 1024 + i] = (uint32_t)(mine >> 32);
        }
    }
}

// ---------------- Kernel C: group-32 greedy sweep + output ----------------
// One wave per batch. remv distributed: lane m holds removed-word m.
// Per group w (rows 32w..32w+31): decisions via broadcast diagonal block
// (uniform in-register chain), updates via per-lane column slice.
__global__ __launch_bounds__(64) void sweep_kernel(
    const uint32_t* __restrict__ suppT, const float4* __restrict__ ws_boxes,
    const float* __restrict__ ws_cls, float* __restrict__ out)
{
    const int b    = blockIdx.x;
    const int lane = threadIdx.x;
    const int myw  = lane & 31;
    const uint32_t* base = suppT + (size_t)b * 32 * 1024;

    uint32_t remv = 0, keptw = 0;
    uint4 dgA[8], clA[8], dgB[8], clB[8];

#define LOADG(W, DG, CL) { \
    const uint4* dp_ = (const uint4*)(base + (W) * 1024 + (W) * 32); \
    const uint4* cp_ = (const uint4*)(base + myw * 1024 + (W) * 32); \
    _Pragma("unroll") \
    for (int k_ = 0; k_ < 8; ++k_) { DG[k_] = dp_[k_]; CL[k_] = cp_[k_]; } }

#define STEP(D, C, BBIT) { \
    uint32_t live_ = (((~cur) >> (BBIT)) & 1u) & (uint32_t)((BBIT) < nb); \
    uint32_t msk_ = (uint32_t)0 - live_; \
    kmask |= (live_ << (BBIT)); \
    cur  |= (D) & msk_; \
    acc  |= (C) & msk_; }

#define PROC(W, DG, CL) { \
    const int nb = ((W) == 31) ? (TOPK - 31 * 32) : 32; \
    uint32_t cur = __shfl(remv, (W)); \
    uint32_t kmask = 0, acc = 0; \
    _Pragma("unroll") \
    for (int k_ = 0; k_ < 8; ++k_) { \
        STEP(DG[k_].x, CL[k_].x, 4 * k_ + 0); \
        STEP(DG[k_].y, CL[k_].y, 4 * k_ + 1); \
        STEP(DG[k_].z, CL[k_].z, 4 * k_ + 2); \
        STEP(DG[k_].w, CL[k_].w, 4 * k_ + 3); \
    } \
    remv |= acc; \
    if (myw == (W)) keptw = kmask; }

    LOADG(0, dgA, clA);
    #pragma unroll 1
    for (int w2 = 0; w2 < 16; ++w2) {
        const int wE = 2 * w2, wO = 2 * w2 + 1;
        LOADG(wO, dgB, clB);          // prefetch odd group
        PROC(wE, dgA, clA);
        if (wO + 1 < 32) LOADG(wO + 1, dgA, clA);   // prefetch next even group
        PROC(wO, dgB, clB);
    }

    __shared__ uint32_t skept[32];
    if (lane < 32) skept[lane] = keptw;
    __syncthreads();

    const float4* bx = ws_boxes + (size_t)b * TOPK;
    const float*  bc = ws_cls + (size_t)b * TOPK;
    float4* outr = (float4*)out + (size_t)b * TOPK;
    float*  outc = out + (size_t)BATCH * TOPK * 4 + (size_t)b * TOPK;
    for (int j = lane; j < TOPK; j += 64) {
        uint32_t keep = (skept[j >> 5] >> (j & 31)) & 1u;
        float4 v = bx[j];
        float cv = bc[j];
        outr[j] = keep ? v : make_float4(0.f, 0.f, 0.f, 0.f);
        outc[j] = keep ? cv : 0.0f;
    }
#undef LOADG
#undef STEP
#undef PROC
}

extern "C" void kernel_launch(void* const* d_in, const int* in_sizes, int n_in,
                              void* d_out, int out_size, void* d_ws, size_t ws_size,
                              hipStream_t stream) {
    (void)in_sizes; (void)n_in; (void)out_size; (void)ws_size;
    const float* reg = (const float*)d_in[0];
    const float* cls = (const float*)d_in[1];
    float* out = (float*)d_out;
    char* ws = (char*)d_ws;

    float4*   ws_boxes = (float4*)ws;                      // 16*1000*16 = 256000 B
    float*    ws_cls   = (float*)(ws + 256000);            // 64000 B
    uint32_t* suppT    = (uint32_t*)(ws + 320000);         // 16*32*1024*4 = 2097152 B

    topk_kernel<<<dim3(BATCH), dim3(1024), 0, stream>>>(reg, cls, ws_boxes, ws_cls);
    iou_kernel<<<dim3(16, BATCH), dim3(256), 0, stream>>>(ws_boxes, suppT);
    sweep_kernel<<<dim3(BATCH), dim3(64), 0, stream>>>(suppT, ws_boxes, ws_cls, out);
}

// Round 4
// 72.770 us; speedup vs baseline: 2.5794x; 1.0266x over previous
//
#include <hip/hip_runtime.h>
#include <stdint.h>

#define BATCH 16
#define NPTS  20000
#define TOPK  1000
#define NKPT  20          // keys per thread (20*1024 >= 20000)
#define NBIN  2048
#define NCOPY 4
#define CANDCAP 2048

__device__ __forceinline__ uint32_t key_desc(float f) {
    // ascending transform, then invert -> sorting ascending by k gives cls descending
    uint32_t u = __float_as_uint(f);
    uint32_t m = (u & 0x80000000u) ? ~u : (u | 0x80000000u);
    return ~m;
}

__device__ __forceinline__ float key_undo(uint32_t k) {
    uint32_t m = ~k;
    uint32_t u = (m & 0x80000000u) ? (m & 0x7FFFFFFFu) : ~m;
    return __uint_as_float(u);
}

// Hierarchical scan over merged 2048-bin histogram (NCOPY copies); finds bin
// containing rank r, writes bin id / rank-within-bin / bin count to shared.
__device__ __forceinline__ void hist_scan_find(
    uint32_t (*wh)[NBIN], uint32_t* wsum, uint32_t* wpre,
    int* sh_T, int* sh_r, int* sh_binc,
    int tid, int wave, int lane, uint32_t r)
{
    uint32_t m0 = 0, m1 = 0;
    #pragma unroll
    for (int cpy = 0; cpy < NCOPY; ++cpy) { m0 += wh[cpy][2*tid]; m1 += wh[cpy][2*tid+1]; }
    uint32_t s = m0 + m1, x = s;
    #pragma unroll
    for (int d = 1; d < 64; d <<= 1) { uint32_t t = __shfl_up(x, d); if (lane >= d) x += t; }
    if (lane == 63) wsum[wave] = x;
    __syncthreads();
    if (wave == 0 && lane < 16) {
        uint32_t v = wsum[lane], y = v;
        #pragma unroll
        for (int d = 1; d < 16; d <<= 1) { uint32_t t = __shfl_up(y, d); if (lane >= d) y += t; }
        wpre[lane] = y - v;
    }
    __syncthreads();
    uint32_t e = wpre[wave] + (x - s);
    if (r >= e && r < e + s) {
        if (r < e + m0) { *sh_T = 2*tid;     *sh_r = (int)(r - e);      *sh_binc = (int)m0; }
        else            { *sh_T = 2*tid + 1; *sh_r = (int)(r - e - m0); *sh_binc = (int)m1; }
    }
}

// Wave-aggregated list push (1 atomic per wave-op). Safe under ragged loops:
// __ballot covers active lanes only.
__device__ __forceinline__ void push64(bool pred, uint64_t val, int* cntr,
                                       uint64_t* list, int lane) {
    uint64_t mask = __ballot(pred);
    if (mask) {
        int first = __ffsll((long long)mask) - 1;
        int base = 0;
        if (lane == first) base = atomicAdd(cntr, (int)__popcll(mask));
        base = __shfl(base, first);
        if (pred) {
            int off = (int)__popcll(mask & ((1ull << lane) - 1ull));
            list[base + off] = val;
        }
    }
}

// Wave 0 picks the r-th smallest of lst[0..n) (n<=64, keys distinct).
__device__ __forceinline__ void wave_select(const uint64_t* lst, int n, int r,
                                            uint64_t* out, int wave, int lane) {
    if (wave == 0) {
        uint64_t my = (lane < n) ? lst[lane] : ~0ull;
        int rank = 0;
        for (int i = 0; i < n; ++i) { uint64_t o = __shfl(my, i); if (o < my) rank++; }
        if (lane < n && rank == r) *out = my;
    }
}

// Exact fallback for heavy ties: block-wide bit binary search over registers.
__device__ uint64_t bit_search(const uint32_t* kreg, uint64_t known, uint64_t kmask,
                               int startbit, uint32_t r, int* sh_c,
                               int tid, int lane) {
    for (int bit = startbit; bit >= 0; --bit) {
        if (tid == 0) *sh_c = 0;
        __syncthreads();
        uint32_t local = 0;
        #pragma unroll
        for (int j = 0; j < NKPT; ++j) {
            int p = tid + j * 1024;
            uint64_t k64 = ((uint64_t)kreg[j] << 32) | (uint32_t)p;
            if (p < NPTS && (k64 & kmask) == known && !((k64 >> bit) & 1ull)) local++;
        }
        #pragma unroll
        for (int d = 1; d < 64; d <<= 1) local += __shfl_xor(local, d);
        if (lane == 0 && local) atomicAdd(sh_c, (int)local);
        __syncthreads();
        uint32_t c0 = (uint32_t)*sh_c;
        if (r >= c0) { known |= 1ull << bit; r -= c0; }
        kmask |= 1ull << bit;
        __syncthreads();
    }
    return known;
}

// ---------------- Kernel A: exact stable top-1000 per batch ----------------
__global__ __launch_bounds__(1024) void topk_kernel(
    const float* __restrict__ reg, const float* __restrict__ cls,
    float4* __restrict__ ws_boxes, float* __restrict__ ws_cls)
{
    __shared__ uint32_t whist[NCOPY][NBIN];
    __shared__ uint32_t wsum[16], wpre[16];
    __shared__ int      sh_T, sh_r, sh_binc, sh_cnt;
    __shared__ uint64_t sh_kthkey;
    __shared__ uint64_t cand[CANDCAP];
    __shared__ uint64_t cand2[64];
    __shared__ uint64_t sel[1024];

    const int b = blockIdx.x, tid = threadIdx.x;
    const int wave = tid >> 6, lane = tid & 63;
    const float* c = cls + (size_t)b * NPTS;

    uint32_t kreg[NKPT];
    #pragma unroll
    for (int j = 0; j < NKPT; ++j) {
        int p = tid + j * 1024;
        kreg[j] = (p < NPTS) ? key_desc(c[p]) : 0xFFFFFFFFu;
    }

    // ---- pass 1: 2048-bin histogram over top 11 key bits ----
    #pragma unroll
    for (int i = 0; i < NCOPY * NBIN / 1024; ++i) ((uint32_t*)whist)[tid + i * 1024] = 0;
    __syncthreads();
    #pragma unroll
    for (int j = 0; j < NKPT; ++j) {
        int p = tid + j * 1024;
        if (p < NPTS) atomicAdd(&whist[wave >> 2][kreg[j] >> 21], 1u);
    }
    __syncthreads();
    hist_scan_find(whist, wsum, wpre, &sh_T, &sh_r, &sh_binc, tid, wave, lane, TOPK - 1);
    __syncthreads();
    const int T1 = sh_T; int r = sh_r; const int cnt1 = sh_binc;
    uint64_t known = (uint64_t)(uint32_t)T1 << 53;

    if (cnt1 <= 64) {
        if (tid == 0) sh_cnt = 0;
        __syncthreads();
        #pragma unroll
        for (int j = 0; j < NKPT; ++j) {
            int p = tid + j * 1024;
            push64(p < NPTS && (kreg[j] >> 21) == (uint32_t)T1,
                   ((uint64_t)kreg[j] << 32) | (uint32_t)p, &sh_cnt, cand2, lane);
        }
        __syncthreads();
        wave_select(cand2, cnt1, r, &sh_kthkey, wave, lane);
        __syncthreads();
    } else if (cnt1 <= CANDCAP) {
        if (tid == 0) sh_cnt = 0;
        __syncthreads();
        #pragma unroll
        for (int j = 0; j < NKPT; ++j) {
            int p = tid + j * 1024;
            push64(p < NPTS && (kreg[j] >> 21) == (uint32_t)T1,
                   ((uint64_t)kreg[j] << 32) | (uint32_t)p, &sh_cnt, cand, lane);
        }
        __syncthreads();
        // ---- pass 2: 2048-bin histogram over next 11 key bits, cand only ----
        #pragma unroll
        for (int i = 0; i < NCOPY * NBIN / 1024; ++i) ((uint32_t*)whist)[tid + i * 1024] = 0;
        __syncthreads();
        for (int i = tid; i < cnt1; i += 1024)
            atomicAdd(&whist[wave >> 2][(uint32_t)((cand[i] >> 42) & 2047)], 1u);
        __syncthreads();
        hist_scan_find(whist, wsum, wpre, &sh_T, &sh_r, &sh_binc, tid, wave, lane, (uint32_t)r);
        __syncthreads();
        const int T2 = sh_T; r = sh_r; const int cnt2 = sh_binc;
        known |= (uint64_t)(uint32_t)T2 << 42;
        if (cnt2 <= 64) {
            if (tid == 0) sh_cnt = 0;
            __syncthreads();
            for (int i = tid; i < cnt1; i += 1024)
                push64(((cand[i] >> 42) & 2047) == (uint64_t)(uint32_t)T2,
                       cand[i], &sh_cnt, cand2, lane);
            __syncthreads();
            wave_select(cand2, cnt2, r, &sh_kthkey, wave, lane);
            __syncthreads();
        } else {
            uint64_t kk = bit_search(kreg, known, 0xFFFFFC0000000000ull, 41,
                                     (uint32_t)r, &sh_cnt, tid, lane);
            if (tid == 0) sh_kthkey = kk;
            __syncthreads();
        }
    } else {
        uint64_t kk = bit_search(kreg, known, 0xFFE0000000000000ull, 52,
                                 (uint32_t)r, &sh_cnt, tid, lane);
        if (tid == 0) sh_kthkey = kk;
        __syncthreads();
    }
    const uint64_t kthkey = sh_kthkey;

    // ---- gather exactly 1000 keys <= kthkey (wave-aggregated) ----
    if (tid == 0) sh_cnt = 0;
    sel[tid] = ~0ull;
    __syncthreads();
    #pragma unroll
    for (int j = 0; j < NKPT; ++j) {
        int p = tid + j * 1024;
        uint64_t key = ((uint64_t)kreg[j] << 32) | (uint32_t)p;
        push64(p < NPTS && key <= kthkey, key, &sh_cnt, sel, lane);
    }
    __syncthreads();

    // ---- hybrid bitonic sort 1024 (LDS only for j>=64; shuffles for j<=32) ----
    uint64_t v = sel[tid];
    for (int k = 2; k <= 1024; k <<= 1) {
        for (int j = k >> 1; j >= 64; j >>= 1) {
            __syncthreads();
            sel[tid] = v;
            __syncthreads();
            uint64_t o = sel[tid ^ j];
            bool upper = (tid & j) != 0;
            bool asc   = (tid & k) == 0;
            v = (upper == asc) ? (v > o ? v : o) : (v < o ? v : o);
        }
        int j0 = (k >> 1) < 64 ? (k >> 1) : 32;
        for (int j = j0; j >= 1; j >>= 1) {
            uint64_t o = __shfl_xor(v, j);
            bool upper = (tid & j) != 0;
            bool asc   = (tid & k) == 0;
            v = (upper == asc) ? (v > o ? v : o) : (v < o ? v : o);
        }
    }

    // ---- write sorted boxes + scores ----
    if (tid < TOPK) {
        int p = (int)(v & 0xFFFFFFFFull);
        ws_boxes[b * TOPK + tid] = ((const float4*)reg)[(size_t)b * NPTS + p];
        ws_cls[b * TOPK + tid] = key_undo((uint32_t)(v >> 32));
    }
}

// ---------------- Kernel B: suppression bitmask, TRANSPOSED layout ----------
// suppT[b][word w][row i] = bits: columns 32w..32w+31 of supp row i.
__global__ __launch_bounds__(256) void iou_kernel(
    const float4* __restrict__ ws_boxes, uint32_t* __restrict__ suppT)
{
    __shared__ float4 boxes[TOPK];
    const int b     = blockIdx.y;
    const int chunk = blockIdx.x;     // 0..15, 63 rows each (1008 >= 1000)
    const int tid   = threadIdx.x;
    for (int j = tid; j < TOPK; j += 256) boxes[j] = ws_boxes[b * TOPK + j];
    __syncthreads();

    const int lane = tid & 63;
    const int wave = tid >> 6;        // 0..3
    const int rbeg = chunk * 63;
    const int rend = (rbeg + 63 < TOPK) ? (rbeg + 63) : TOPK;
    uint32_t* t = suppT + (size_t)b * 32 * 1024;

    for (int i = rbeg + wave; i < rend; i += 4) {
        float4 a = boxes[i];
        float areaA = (a.z - a.x) * (a.w - a.y);
        uint64_t mine = 0;
        #pragma unroll
        for (int w = 0; w < 16; ++w) {
            int col = (w << 6) | lane;
            bool sup = false;
            if (col < TOPK) {
                float4 bb = boxes[col];
                float xx1 = fmaxf(a.x, bb.x);
                float yy1 = fmaxf(a.y, bb.y);
                float xx2 = fminf(a.z, bb.z);
                float yy2 = fminf(a.w, bb.w);
                float iw = fmaxf(xx2 - xx1, 0.0f);
                float ih = fmaxf(yy2 - yy1, 0.0f);
                float inter = iw * ih;
                float areaB = (bb.z - bb.x) * (bb.w - bb.y);
                float iou = inter / (areaA + areaB - inter);
                sup = (iou >= 0.5f);
            }
            uint64_t m = __ballot(sup);
            if (lane == w) mine = m;
        }
        if (lane < 16) {
            t[(2 * lane + 0) * 1024 + i] = (uint32_t)(mine & 0xFFFFFFFFull);
            t[(2 * lane + 1) * 1024 + i] = (uint32_t)(mine >> 32);
        }
    }
}

// ---------------- Kernel C: group-32 greedy sweep + output ----------------
__global__ __launch_bounds__(64) void sweep_kernel(
    const uint32_t* __restrict__ suppT, const float4* __restrict__ ws_boxes,
    const float* __restrict__ ws_cls, float* __restrict__ out)
{
    const int b    = blockIdx.x;
    const int lane = threadIdx.x;
    const int myw  = lane & 31;
    const uint32_t* base = suppT + (size_t)b * 32 * 1024;

    uint32_t remv = 0, keptw = 0;
    uint4 dgA[8], clA[8], dgB[8], clB[8];

#define LOADG(W, DG, CL) { \
    const uint4* dp_ = (const uint4*)(base + (W) * 1024 + (W) * 32); \
    const uint4* cp_ = (const uint4*)(base + myw * 1024 + (W) * 32); \
    _Pragma("unroll") \
    for (int k_ = 0; k_ < 8; ++k_) { DG[k_] = dp_[k_]; CL[k_] = cp_[k_]; } }

#define STEP(D, C, BBIT) { \
    uint32_t live_ = (((~cur) >> (BBIT)) & 1u) & (uint32_t)((BBIT) < nb); \
    uint32_t msk_ = (uint32_t)0 - live_; \
    kmask |= (live_ << (BBIT)); \
    cur  |= (D) & msk_; \
    acc  |= (C) & msk_; }

#define PROC(W, DG, CL) { \
    const int nb = ((W) == 31) ? (TOPK - 31 * 32) : 32; \
    uint32_t cur = __shfl(remv, (W)); \
    uint32_t kmask = 0, acc = 0; \
    _Pragma("unroll") \
    for (int k_ = 0; k_ < 8; ++k_) { \
        STEP(DG[k_].x, CL[k_].x, 4 * k_ + 0); \
        STEP(DG[k_].y, CL[k_].y, 4 * k_ + 1); \
        STEP(DG[k_].z, CL[k_].z, 4 * k_ + 2); \
        STEP(DG[k_].w, CL[k_].w, 4 * k_ + 3); \
    } \
    remv |= acc; \
    if (myw == (W)) keptw = kmask; }

    LOADG(0, dgA, clA);
    #pragma unroll 1
    for (int w2 = 0; w2 < 16; ++w2) {
        const int wE = 2 * w2, wO = 2 * w2 + 1;
        LOADG(wO, dgB, clB);          // prefetch odd group
        PROC(wE, dgA, clA);
        if (wO + 1 < 32) LOADG(wO + 1, dgA, clA);   // prefetch next even group
        PROC(wO, dgB, clB);
    }

    __shared__ uint32_t skept[32];
    if (lane < 32) skept[lane] = keptw;
    __syncthreads();

    const float4* bx = ws_boxes + (size_t)b * TOPK;
    const float*  bc = ws_cls + (size_t)b * TOPK;
    float4* outr = (float4*)out + (size_t)b * TOPK;
    float*  outc = out + (size_t)BATCH * TOPK * 4 + (size_t)b * TOPK;
    for (int j = lane; j < TOPK; j += 64) {
        uint32_t keep = (skept[j >> 5] >> (j & 31)) & 1u;
        float4 v = bx[j];
        float cv = bc[j];
        outr[j] = keep ? v : make_float4(0.f, 0.f, 0.f, 0.f);
        outc[j] = keep ? cv : 0.0f;
    }
#undef LOADG
#undef STEP
#undef PROC
}

extern "C" void kernel_launch(void* const* d_in, const int* in_sizes, int n_in,
                              void* d_out, int out_size, void* d_ws, size_t ws_size,
                              hipStream_t stream) {
    (void)in_sizes; (void)n_in; (void)out_size; (void)ws_size;
    const float* reg = (const float*)d_in[0];
    const float* cls = (const float*)d_in[1];
    float* out = (float*)d_out;
    char* ws = (char*)d_ws;

    float4*   ws_boxes = (float4*)ws;                      // 16*1000*16 = 256000 B
    float*    ws_cls   = (float*)(ws + 256000);            // 64000 B
    uint32_t* suppT    = (uint32_t*)(ws + 320000);         // 16*32*1024*4 = 2097152 B

    topk_kernel<<<dim3(BATCH), dim3(1024), 0, stream>>>(reg, cls, ws_boxes, ws_cls);
    iou_kernel<<<dim3(16, BATCH), dim3(256), 0, stream>>>(ws_boxes, suppT);
    sweep_kernel<<<dim3(BATCH), dim3(64), 0, stream>>>(suppT, ws_boxes, ws_cls, out);
}